// Round 1
// baseline (699.260 us; speedup 1.0000x reference)
//
#include <hip/hip_runtime.h>

typedef __attribute__((ext_vector_type(4))) float f32x4;
typedef __attribute__((ext_vector_type(8))) __bf16 bf16x8;
typedef __attribute__((ext_vector_type(8))) unsigned short u16x8;
typedef unsigned short ushort_t;

// ---------- bf16 helpers (bit-level, RNE) ----------
__device__ __forceinline__ unsigned short f2bf(float x) {
  unsigned u = __builtin_bit_cast(unsigned, x);
  u += 0x7fffu + ((u >> 16) & 1u);
  return (unsigned short)(u >> 16);
}
__device__ __forceinline__ float bf2f(unsigned short h) {
  unsigned u = ((unsigned)h) << 16;
  return __builtin_bit_cast(float, u);
}

// ---------- async global->LDS (16B per lane) ----------
__device__ __forceinline__ void gload_lds16(const void* g, void* l) {
  __builtin_amdgcn_global_load_lds(
      (const __attribute__((address_space(1))) unsigned int*)g,
      (__attribute__((address_space(3))) unsigned int*)l, 16, 0, 0);
}

// ---------- f32 -> bf16 conversion (8 elems/thread) ----------
__global__ __launch_bounds__(256) void k_f32_to_bf16(
    const float* __restrict__ src, ushort_t* __restrict__ dst, int n8) {
  int i = blockIdx.x * 256 + threadIdx.x;
  if (i >= n8) return;
  float4 a = ((const float4*)src)[i * 2 + 0];
  float4 b = ((const float4*)src)[i * 2 + 1];
  u16x8 o;
  o[0] = f2bf(a.x); o[1] = f2bf(a.y); o[2] = f2bf(a.z); o[3] = f2bf(a.w);
  o[4] = f2bf(b.x); o[5] = f2bf(b.y); o[6] = f2bf(b.z); o[7] = f2bf(b.w);
  ((u16x8*)dst)[i] = o;
}

// ---------- RoPE (in-place on bf16 QKV buffer) ----------
// QKV row layout: [Q 0..4095 | K 4096..5119 | V 5120..5887], ld = 5888
__global__ __launch_bounds__(256) void k_rope(
    ushort_t* __restrict__ QKV, const int* __restrict__ pos_ids) {
  int idx = blockIdx.x * 256 + threadIdx.x;           // T*40*32 = 5,242,880
  if (idx >= 4096 * 40 * 32) return;
  int d = idx & 31;
  int rem = idx >> 5;
  int hh = rem % 40;          // 0..31 Q heads, 32..39 K heads
  int tk = rem / 40;          // token 0..4095
  int pos = pos_ids[tk];
  // inv_freq = 10000^(-d/32) = exp2(-d * log2(10000)/32)
  float inv = exp2f(-(float)d * (13.287712379549449f / 32.0f));
  float ang = (float)pos * inv;
  float s, c;
  __sincosf(ang, &s, &c);
  int col = (hh < 32) ? (hh * 128 + d) : (4096 + (hh - 32) * 128 + d);
  ushort_t* p = QKV + (size_t)tk * 5888 + col;
  float x1 = bf2f(p[0]);
  float x2 = bf2f(p[32]);
  p[0]  = f2bf(x1 * c - x2 * s);
  p[32] = f2bf(x2 * c + x1 * s);
}

// ---------- bf16 B^T GEMM: C[M,N] = A[M,K] * B[N,K]^T ----------
// 128x128 tile, BK=64, 4 waves (2x2), global_load_lds w=16, XOR-swizzled LDS.
template <int OUT_BF16>
__global__ __launch_bounds__(256, 2) void k_gemm_bt(
    const ushort_t* __restrict__ A, const ushort_t* __restrict__ B,
    void* __restrict__ C, int K, int lda, int ldb, int ldc) {
  __shared__ ushort_t lA[128 * 64];   // rows of 128B, content pre-swizzled
  __shared__ ushort_t lB[128 * 64];
  const int t = threadIdx.x;
  const int ln = t & 63, w = t >> 6;
  const int fr = ln & 15, fg = ln >> 4;
  const int m0 = blockIdx.x * 128, n0 = blockIdx.y * 128;
  const int wr = (w >> 1) * 64, wc = (w & 1) * 64;

  // staging: issue i covers LDS bytes [i*4096 + t*16); row = i*32 + (t>>3)
  // src in-row element = ((t&7)*16 ^ ((row&7)<<4))/2  (row&7 == (t>>3)&7)
  const int srow = t >> 3;
  const int scol = ((((t & 7) * 16) ^ ((srow & 7) << 4)) >> 1);
  const ushort_t* pA = A + (srow + m0) * lda + scol;
  const ushort_t* pB = B + (srow + n0) * ldb + scol;
  char* lAb = (char*)lA + (w << 10);
  char* lBb = (char*)lB + (w << 10);

  f32x4 acc[4][4] = {};

  for (int k0 = 0; k0 < K; k0 += 64) {
    __syncthreads();
#pragma unroll
    for (int i = 0; i < 4; ++i) {
      gload_lds16(pA + i * 32 * lda + k0, lAb + i * 4096);
      gload_lds16(pB + i * 32 * ldb + k0, lBb + i * 4096);
    }
    __syncthreads();
#pragma unroll
    for (int kh = 0; kh < 2; ++kh) {
      bf16x8 af[4], bfv[4];
#pragma unroll
      for (int m = 0; m < 4; ++m) {
        int row = wr + m * 16 + fr;
        af[m] = *(const bf16x8*)((const char*)lA + row * 128 +
                                 ((kh * 64 + fg * 16) ^ ((row & 7) << 4)));
      }
#pragma unroll
      for (int n = 0; n < 4; ++n) {
        int row = wc + n * 16 + fr;
        bfv[n] = *(const bf16x8*)((const char*)lB + row * 128 +
                                  ((kh * 64 + fg * 16) ^ ((row & 7) << 4)));
      }
#pragma unroll
      for (int m = 0; m < 4; ++m)
#pragma unroll
        for (int n = 0; n < 4; ++n)
          acc[m][n] = __builtin_amdgcn_mfma_f32_16x16x32_bf16(
              af[m], bfv[n], acc[m][n], 0, 0, 0);
    }
  }
  // epilogue: C row = m0+wr+m*16+fg*4+j, col = n0+wc+n*16+fr
#pragma unroll
  for (int m = 0; m < 4; ++m)
#pragma unroll
    for (int n = 0; n < 4; ++n) {
      int row = m0 + wr + m * 16 + fg * 4;
      int col = n0 + wc + n * 16 + fr;
#pragma unroll
      for (int j = 0; j < 4; ++j) {
        if (OUT_BF16)
          ((ushort_t*)C)[(size_t)(row + j) * ldc + col] = f2bf(acc[m][n][j]);
        else
          ((float*)C)[(size_t)(row + j) * ldc + col] = acc[m][n][j];
      }
    }
}

// ---------- causal GQA flash attention ----------
// grid (S/128, NH, B), 256 thr. Wave w owns q rows [qt*128+w*32, +32).
__global__ __launch_bounds__(256, 2) void k_attn(
    const ushort_t* __restrict__ QKV, ushort_t* __restrict__ O) {
  __shared__ ushort_t lK[64 * 128];      // swizzled, rows 256B
  __shared__ ushort_t lV[96 * 72];       // V^T [c][kv], pad 64->72
  __shared__ ushort_t lP[4][32 * 72];    // per-wave P, pad 64->72

  const int t = threadIdx.x, ln = t & 63, w = t >> 6;
  const int fr = ln & 15, fg = ln >> 4;
  const int qt = blockIdx.x, h = blockIdx.y, b = blockIdx.z;
  const int hk = h >> 2;
  const int q0 = qt * 128 + w * 32;
  const int tb = b * 2048;

  // Q fragments in regs: rows q0+r*16+fr, dims kb*32+fg*8 (8 contiguous)
  bf16x8 qf[2][4];
#pragma unroll
  for (int r = 0; r < 2; ++r)
#pragma unroll
    for (int kb = 0; kb < 4; ++kb)
      qf[r][kb] = *(const bf16x8*)(QKV + (size_t)(tb + q0 + r * 16 + fr) * 5888 +
                                   h * 128 + kb * 32 + fg * 8);

  f32x4 oacc[2][6] = {};
  float mrow[2][4], lrow[2][4];
#pragma unroll
  for (int r = 0; r < 2; ++r)
#pragma unroll
    for (int j = 0; j < 4; ++j) { mrow[r][j] = -1e30f; lrow[r][j] = 0.f; }

  const int krow = t >> 4;                                          // K stage
  const int kse = ((((t & 15) * 16) ^ (((t >> 4) & 7) << 4)) >> 1);
  const int vr = t >> 2, cg = (t & 3) * 24;                         // V stage

  const int nkt = (qt + 1) * 2;
  for (int kt = 0; kt < nkt; ++kt) {
    const int kb0 = kt * 64;
    __syncthreads();
    {
      const ushort_t* pK =
          QKV + (size_t)(tb + kb0 + krow) * 5888 + 4096 + hk * 128 + kse;
#pragma unroll
      for (int i = 0; i < 4; ++i)
        gload_lds16(pK + (size_t)i * 16 * 5888, (char*)lK + i * 4096 + (w << 10));
      const ushort_t* pV =
          QKV + (size_t)(tb + kb0 + vr) * 5888 + 5120 + hk * 96 + cg;
#pragma unroll
      for (int jj = 0; jj < 3; ++jj) {
        u16x8 v = *(const u16x8*)(pV + jj * 8);
#pragma unroll
        for (int e = 0; e < 8; ++e) lV[(cg + jj * 8 + e) * 72 + vr] = v[e];
      }
    }
    __syncthreads();
    if (kb0 <= q0 + 31) {   // wave has at least one unmasked (q,k)
      // ---- S = Q K^T ----
      f32x4 s[2][4] = {};
#pragma unroll
      for (int cb = 0; cb < 4; ++cb) {
        bf16x8 kf[4];
        int kv = cb * 16 + fr;
#pragma unroll
        for (int kb = 0; kb < 4; ++kb)
          kf[kb] = *(const bf16x8*)((const char*)lK + kv * 256 +
                                    ((kb * 64 + fg * 16) ^ ((kv & 7) << 4)));
#pragma unroll
        for (int r = 0; r < 2; ++r)
#pragma unroll
          for (int kb = 0; kb < 4; ++kb)
            s[r][cb] = __builtin_amdgcn_mfma_f32_16x16x32_bf16(
                qf[r][kb], kf[kb], s[r][cb], 0, 0, 0);
      }
      const float sc = 0.088388347648318447f;   // 1/sqrt(128)
      const float l2e = 1.4426950408889634f;
      // ---- mask + online softmax ----
#pragma unroll
      for (int r = 0; r < 2; ++r) {
#pragma unroll
        for (int j = 0; j < 4; ++j) {
          int qrow = q0 + r * 16 + fg * 4 + j;
          float rm = -1e30f;
#pragma unroll
          for (int cb = 0; cb < 4; ++cb) {
            int kcol = kb0 + cb * 16 + fr;
            float v = (kcol <= qrow) ? s[r][cb][j] * sc : -1e30f;
            s[r][cb][j] = v;
            rm = fmaxf(rm, v);
          }
#pragma unroll
          for (int mk = 1; mk < 16; mk <<= 1)
            rm = fmaxf(rm, __shfl_xor(rm, mk, 64));
          float mnew = fmaxf(mrow[r][j], rm);
          float scalef = exp2f((mrow[r][j] - mnew) * l2e);
          mrow[r][j] = mnew;
          float ps = 0.f;
#pragma unroll
          for (int cb = 0; cb < 4; ++cb) {
            float p = exp2f((s[r][cb][j] - mnew) * l2e);
            s[r][cb][j] = p;
            ps += p;
          }
#pragma unroll
          for (int mk = 1; mk < 16; mk <<= 1) ps += __shfl_xor(ps, mk, 64);
          lrow[r][j] = lrow[r][j] * scalef + ps;
#pragma unroll
          for (int c6 = 0; c6 < 6; ++c6) oacc[r][c6][j] *= scalef;
        }
      }
      // ---- P -> LDS (bf16) ----
#pragma unroll
      for (int r = 0; r < 2; ++r)
#pragma unroll
        for (int cb = 0; cb < 4; ++cb)
#pragma unroll
          for (int j = 0; j < 4; ++j)
            lP[w][(r * 16 + fg * 4 + j) * 72 + cb * 16 + fr] =
                f2bf(s[r][cb][j]);
      asm volatile("s_waitcnt lgkmcnt(0)" ::: "memory");
      __builtin_amdgcn_sched_barrier(0);
      // ---- O += P V ----
#pragma unroll
      for (int kh = 0; kh < 2; ++kh) {
        bf16x8 pa[2], vf[6];
#pragma unroll
        for (int r = 0; r < 2; ++r)
          pa[r] = *(const bf16x8*)(&lP[w][(r * 16 + fr) * 72 + kh * 32 + fg * 8]);
#pragma unroll
        for (int c6 = 0; c6 < 6; ++c6)
          vf[c6] = *(const bf16x8*)(&lV[(c6 * 16 + fr) * 72 + kh * 32 + fg * 8]);
#pragma unroll
        for (int r = 0; r < 2; ++r)
#pragma unroll
          for (int c6 = 0; c6 < 6; ++c6)
            oacc[r][c6] = __builtin_amdgcn_mfma_f32_16x16x32_bf16(
                pa[r], vf[c6], oacc[r][c6], 0, 0, 0);
      }
    }
  }
  // ---- epilogue: O / l -> attn_out (T, 3072) bf16 ----
#pragma unroll
  for (int r = 0; r < 2; ++r)
#pragma unroll
    for (int c6 = 0; c6 < 6; ++c6)
#pragma unroll
      for (int j = 0; j < 4; ++j) {
        int row = q0 + r * 16 + fg * 4 + j;
        float v = oacc[r][c6][j] / lrow[r][j];
        O[(size_t)(tb + row) * 3072 + h * 96 + c6 * 16 + fr] = f2bf(v);
      }
}

// ---------------- launcher ----------------
extern "C" void kernel_launch(void* const* d_in, const int* in_sizes, int n_in,
                              void* d_out, int out_size, void* d_ws,
                              size_t ws_size, hipStream_t stream) {
  const float* X  = (const float*)d_in[0];
  const int*   pos = (const int*)d_in[1];
  const float* Wq = (const float*)d_in[2];
  const float* Wk = (const float*)d_in[3];
  const float* Wv = (const float*)d_in[4];
  const float* Wo = (const float*)d_in[5];
  float* out = (float*)d_out;

  // ws layout (bf16 elements): Xb 16.7M | Wob 12.6M | QKV 24.1M | AO 12.6M
  // total = 132,120,576 bytes
  ushort_t* Xb    = (ushort_t*)d_ws;
  ushort_t* Wob   = Xb + 16777216;
  ushort_t* QKV   = Wob + 12582912;
  ushort_t* AO    = QKV + 24117248;
  // concatenated bf16 [Wq;Wk;Wv] staged in d_out (48.2MB <= 64MB), consumed
  // by the QKV GEMM before d_out is overwritten by the final projection.
  ushort_t* Wqkvb = (ushort_t*)d_out;

  // conversions (n/8 threads each)
  k_f32_to_bf16<<<8192, 256, 0, stream>>>(X, Xb, 2097152);
  k_f32_to_bf16<<<8192, 256, 0, stream>>>(Wq, Wqkvb, 2097152);
  k_f32_to_bf16<<<2048, 256, 0, stream>>>(Wk, Wqkvb + 16777216, 524288);
  k_f32_to_bf16<<<1536, 256, 0, stream>>>(Wv, Wqkvb + 20971520, 393216);
  k_f32_to_bf16<<<6144, 256, 0, stream>>>(Wo, Wob, 1572864);

  // QKV projection: (4096 x 4096) * (5888 x 4096)^T -> (4096 x 5888) bf16
  k_gemm_bt<1><<<dim3(32, 46), 256, 0, stream>>>(Xb, Wqkvb, QKV, 4096, 4096,
                                                 4096, 5888);
  // RoPE on Q and K columns
  k_rope<<<20480, 256, 0, stream>>>(QKV, pos);
  // causal GQA flash attention -> (4096 x 3072) bf16
  k_attn<<<dim3(16, 32, 2), 256, 0, stream>>>(QKV, AO);
  // output projection: (4096 x 3072) * (4096 x 3072)^T -> (4096 x 4096) f32
  k_gemm_bt<0><<<dim3(32, 32), 256, 0, stream>>>(AO, Wob, out, 3072, 3072,
                                                 3072, 4096);
}

// Round 2
// 621.177 us; speedup vs baseline: 1.1257x; 1.1257x over previous
//
#include <hip/hip_runtime.h>

typedef __attribute__((ext_vector_type(4))) float f32x4;
typedef __attribute__((ext_vector_type(8))) __bf16 bf16x8;
typedef __attribute__((ext_vector_type(8))) unsigned short u16x8;
typedef __attribute__((ext_vector_type(4))) unsigned short u16x4;
typedef __attribute__((ext_vector_type(4))) short s16x4;
typedef unsigned short ushort_t;

#if defined(__has_builtin)
#  if __has_builtin(__builtin_amdgcn_mfma_f32_16x16x16bf16_1k)
#    define HAS_MFMA16 1
#  else
#    define HAS_MFMA16 0
#  endif
#else
#  define HAS_MFMA16 0
#endif

constexpr int VPAD = HAS_MFMA16 ? 68 : 72;   // 68: b64-aligned, 2-way write conflicts

// ---------- bf16 helpers (bit-level, RNE) ----------
__device__ __forceinline__ unsigned short f2bf(float x) {
  unsigned u = __builtin_bit_cast(unsigned, x);
  u += 0x7fffu + ((u >> 16) & 1u);
  return (unsigned short)(u >> 16);
}
__device__ __forceinline__ float bf2f(unsigned short h) {
  unsigned u = ((unsigned)h) << 16;
  return __builtin_bit_cast(float, u);
}

// ---------- async global->LDS (16B per lane) ----------
__device__ __forceinline__ void gload_lds16(const void* g, void* l) {
  __builtin_amdgcn_global_load_lds(
      (const __attribute__((address_space(1))) unsigned int*)g,
      (__attribute__((address_space(3))) unsigned int*)l, 16, 0, 0);
}

// ---------- f32 -> bf16 conversion (8 elems/thread) ----------
__global__ __launch_bounds__(256) void k_f32_to_bf16(
    const float* __restrict__ src, ushort_t* __restrict__ dst, int n8) {
  int i = blockIdx.x * 256 + threadIdx.x;
  if (i >= n8) return;
  float4 a = ((const float4*)src)[i * 2 + 0];
  float4 b = ((const float4*)src)[i * 2 + 1];
  u16x8 o;
  o[0] = f2bf(a.x); o[1] = f2bf(a.y); o[2] = f2bf(a.z); o[3] = f2bf(a.w);
  o[4] = f2bf(b.x); o[5] = f2bf(b.y); o[6] = f2bf(b.z); o[7] = f2bf(b.w);
  ((u16x8*)dst)[i] = o;
}

// ---------- RoPE (in-place on bf16 QKV buffer) ----------
__global__ __launch_bounds__(256) void k_rope(
    ushort_t* __restrict__ QKV, const int* __restrict__ pos_ids) {
  int idx = blockIdx.x * 256 + threadIdx.x;
  if (idx >= 4096 * 40 * 32) return;
  int d = idx & 31;
  int rem = idx >> 5;
  int hh = rem % 40;
  int tk = rem / 40;
  int pos = pos_ids[tk];
  float inv = exp2f(-(float)d * (13.287712379549449f / 32.0f));
  float ang = (float)pos * inv;
  float s, c;
  __sincosf(ang, &s, &c);
  int col = (hh < 32) ? (hh * 128 + d) : (4096 + (hh - 32) * 128 + d);
  ushort_t* p = QKV + (size_t)tk * 5888 + col;
  float x1 = bf2f(p[0]);
  float x2 = bf2f(p[32]);
  p[0]  = f2bf(x1 * c - x2 * s);
  p[32] = f2bf(x2 * c + x1 * s);
}

// ---------- bf16 B^T GEMM: C[M,N] = A[M,K] * B[N,K]^T ----------
template <int OUT_BF16>
__global__ __launch_bounds__(256, 2) void k_gemm_bt(
    const ushort_t* __restrict__ A, const ushort_t* __restrict__ B,
    void* __restrict__ C, int K, int lda, int ldb, int ldc) {
  __shared__ ushort_t lA[128 * 64];
  __shared__ ushort_t lB[128 * 64];
  const int t = threadIdx.x;
  const int ln = t & 63, w = t >> 6;
  const int fr = ln & 15, fg = ln >> 4;
  // bijective XCD-aware remap (m204)
  const int nwg = gridDim.x * gridDim.y;
  const int orig = blockIdx.y * gridDim.x + blockIdx.x;
  const int qq = nwg >> 3, rr = nwg & 7;
  const int xcd = orig & 7, off = orig >> 3;
  const int wg = (xcd < rr ? xcd * (qq + 1) : rr * (qq + 1) + (xcd - rr) * qq) + off;
  const int m0 = (wg % gridDim.x) * 128, n0 = (wg / gridDim.x) * 128;
  const int wr = (w >> 1) * 64, wc = (w & 1) * 64;

  const int srow = t >> 3;
  const int scol = ((((t & 7) * 16) ^ ((srow & 7) << 4)) >> 1);
  const ushort_t* pA = A + (srow + m0) * lda + scol;
  const ushort_t* pB = B + (srow + n0) * ldb + scol;
  char* lAb = (char*)lA + (w << 10);
  char* lBb = (char*)lB + (w << 10);

  f32x4 acc[4][4] = {};

  for (int k0 = 0; k0 < K; k0 += 64) {
    __syncthreads();
#pragma unroll
    for (int i = 0; i < 4; ++i) {
      gload_lds16(pA + i * 32 * lda + k0, lAb + i * 4096);
      gload_lds16(pB + i * 32 * ldb + k0, lBb + i * 4096);
    }
    __syncthreads();
#pragma unroll
    for (int kh = 0; kh < 2; ++kh) {
      bf16x8 af[4], bfv[4];
#pragma unroll
      for (int m = 0; m < 4; ++m) {
        int row = wr + m * 16 + fr;
        af[m] = *(const bf16x8*)((const char*)lA + row * 128 +
                                 ((kh * 64 + fg * 16) ^ ((row & 7) << 4)));
      }
#pragma unroll
      for (int n = 0; n < 4; ++n) {
        int row = wc + n * 16 + fr;
        bfv[n] = *(const bf16x8*)((const char*)lB + row * 128 +
                                  ((kh * 64 + fg * 16) ^ ((row & 7) << 4)));
      }
#pragma unroll
      for (int m = 0; m < 4; ++m)
#pragma unroll
        for (int n = 0; n < 4; ++n)
          acc[m][n] = __builtin_amdgcn_mfma_f32_16x16x32_bf16(
              af[m], bfv[n], acc[m][n], 0, 0, 0);
    }
  }
#pragma unroll
  for (int m = 0; m < 4; ++m)
#pragma unroll
    for (int n = 0; n < 4; ++n) {
      int row = m0 + wr + m * 16 + fg * 4;
      int col = n0 + wc + n * 16 + fr;
#pragma unroll
      for (int j = 0; j < 4; ++j) {
        if (OUT_BF16)
          ((ushort_t*)C)[(size_t)(row + j) * ldc + col] = f2bf(acc[m][n][j]);
        else
          ((float*)C)[(size_t)(row + j) * ldc + col] = acc[m][n][j];
      }
    }
}

// ---------- causal GQA flash attention (S^T / O^T formulation) ----------
// grid (16, 32, 2), 256 thr. Wave w owns q rows [qt*128+w*32, +32).
__global__ __launch_bounds__(256, 2) void k_attn(
    const ushort_t* __restrict__ QKV, ushort_t* __restrict__ O) {
  __shared__ ushort_t lK[64 * 128];        // swizzled rows of 256B
  __shared__ ushort_t lV[96 * VPAD];       // V^T [c][kv]
#if !HAS_MFMA16
  __shared__ ushort_t lP[4][32 * 72];
#endif
  const int t = threadIdx.x, ln = t & 63, w = t >> 6;
  const int fr = ln & 15, fg = ln >> 4;
  const int h = blockIdx.y, b = blockIdx.z;
  // h-parity qt remap: per-CU work becomes uniform (blocks id, id+256,..
  // share qt; pairing qt with 15-qt balances them)
  const int qt = (h & 1) ? ((int)gridDim.x - 1 - (int)blockIdx.x)
                         : (int)blockIdx.x;
  const int hk = h >> 2;
  const int q0 = qt * 128 + w * 32;
  const int tb = b * 2048;

  // Q B-frags: lane (fr,fg) holds Q[q0+rq*16+fr][kb*32+fg*8 ..+7]
  bf16x8 qf[2][4];
#pragma unroll
  for (int rq = 0; rq < 2; ++rq)
#pragma unroll
    for (int kb = 0; kb < 4; ++kb)
      qf[rq][kb] = *(const bf16x8*)(QKV +
                    (size_t)(tb + q0 + rq * 16 + fr) * 5888 + h * 128 +
                    kb * 32 + fg * 8);

  f32x4 oacc[6][2] = {};           // O^T: [c6][rq], col(lane&15)=q, row=c
  float mreg[2] = {-1e30f, -1e30f};
  float lreg[2] = {0.f, 0.f};

  const int krow = t >> 4;
  const int kse = ((((t & 15) * 16) ^ (((t >> 4) & 7) << 4)) >> 1);
  const int vr = t >> 2, cg = (t & 3) * 24;

  const int nkt = (qt + 1) * 2;
  for (int kt = 0; kt < nkt; ++kt) {
    const int kb0 = kt * 64;
    __syncthreads();
    {
      const ushort_t* pK =
          QKV + (size_t)(tb + kb0 + krow) * 5888 + 4096 + hk * 128 + kse;
#pragma unroll
      for (int i = 0; i < 4; ++i)
        gload_lds16(pK + (size_t)i * 16 * 5888,
                    (char*)lK + i * 4096 + (w << 10));
      const ushort_t* pV =
          QKV + (size_t)(tb + kb0 + vr) * 5888 + 5120 + hk * 96 + cg;
#pragma unroll
      for (int jj = 0; jj < 3; ++jj) {
        u16x8 v = *(const u16x8*)(pV + jj * 8);
#pragma unroll
        for (int e = 0; e < 8; ++e) lV[(cg + jj * 8 + e) * VPAD + vr] = v[e];
      }
    }
    __syncthreads();
    if (kb0 <= q0 + 31) {
      // ---- S^T = K Q^T : s[cb][rq], lane holds S[k=kb0+cb*16+fg*4+j][q0+rq*16+fr]
      f32x4 s[4][2] = {};
#pragma unroll
      for (int cb = 0; cb < 4; ++cb) {
        const int kv = cb * 16 + fr;
        bf16x8 kf[4];
#pragma unroll
        for (int kb = 0; kb < 4; ++kb)
          kf[kb] = *(const bf16x8*)((const char*)lK + kv * 256 +
                                    ((kb * 64 + fg * 16) ^ ((kv & 7) << 4)));
#pragma unroll
        for (int rq = 0; rq < 2; ++rq)
#pragma unroll
          for (int kb = 0; kb < 4; ++kb)
            s[cb][rq] = __builtin_amdgcn_mfma_f32_16x16x32_bf16(
                kf[kb], qf[rq][kb], s[cb][rq], 0, 0, 0);
      }
      const float sc = 0.088388347648318447f;   // 1/sqrt(128)
      const float l2e = 1.4426950408889634f;
      const bool notfull = (kb0 + 63 > q0);
#pragma unroll
      for (int rq = 0; rq < 2; ++rq) {
        const int qrel = q0 + rq * 16 + fr - kb0;   // k_local <= qrel allowed
        float rm = -1e30f;
#pragma unroll
        for (int cb = 0; cb < 4; ++cb)
#pragma unroll
          for (int j = 0; j < 4; ++j) {
            float v = s[cb][rq][j] * sc;
            if (notfull && (cb * 16 + fg * 4 + j > qrel)) v = -1e30f;
            s[cb][rq][j] = v;
            rm = fmaxf(rm, v);
          }
        rm = fmaxf(rm, __shfl_xor(rm, 16, 64));
        rm = fmaxf(rm, __shfl_xor(rm, 32, 64));
        const float mnew = fmaxf(mreg[rq], rm);
        const float scalef = exp2f((mreg[rq] - mnew) * l2e);
        mreg[rq] = mnew;
        float ps = 0.f;
#pragma unroll
        for (int cb = 0; cb < 4; ++cb)
#pragma unroll
          for (int j = 0; j < 4; ++j) {
            float p = exp2f((s[cb][rq][j] - mnew) * l2e);
            s[cb][rq][j] = p;
            ps += p;
          }
        ps += __shfl_xor(ps, 16, 64);
        ps += __shfl_xor(ps, 32, 64);
        lreg[rq] = lreg[rq] * scalef + ps;
#pragma unroll
        for (int c6 = 0; c6 < 6; ++c6) oacc[c6][rq] *= scalef;
      }
      // ---- pack P to bf16 frags (lane-local, no data movement) ----
      s16x4 pb[4][2];
#pragma unroll
      for (int cb = 0; cb < 4; ++cb)
#pragma unroll
        for (int rq = 0; rq < 2; ++rq) {
          s16x4 v;
#pragma unroll
          for (int j = 0; j < 4; ++j) v[j] = (short)f2bf(s[cb][rq][j]);
          pb[cb][rq] = v;
        }
      // ---- O^T += V^T P : A = V^T frag (from lV), B = P frag (in regs) ----
#if HAS_MFMA16
#pragma unroll
      for (int c6 = 0; c6 < 6; ++c6)
#pragma unroll
        for (int cb = 0; cb < 4; ++cb) {
          s16x4 va = *(const s16x4*)(&lV[(c6 * 16 + fr) * VPAD + cb * 16 + fg * 4]);
#pragma unroll
          for (int rq = 0; rq < 2; ++rq)
            oacc[c6][rq] = __builtin_amdgcn_mfma_f32_16x16x16bf16_1k(
                va, pb[cb][rq], oacc[c6][rq], 0, 0, 0);
        }
#else
      // fallback: per-wave LDS round-trip, K=32 MFMA
#pragma unroll
      for (int cb = 0; cb < 4; ++cb)
#pragma unroll
        for (int rq = 0; rq < 2; ++rq)
          *(s16x4*)(&lP[w][(rq * 16 + fr) * 72 + cb * 16 + fg * 4]) = pb[cb][rq];
#pragma unroll
      for (int kh = 0; kh < 2; ++kh) {
        bf16x8 pa[2];
#pragma unroll
        for (int rq = 0; rq < 2; ++rq)
          pa[rq] = *(const bf16x8*)(&lP[w][(rq * 16 + fr) * 72 + kh * 32 + fg * 8]);
#pragma unroll
        for (int c6 = 0; c6 < 6; ++c6) {
          bf16x8 va = *(const bf16x8*)(&lV[(c6 * 16 + fr) * VPAD + kh * 32 + fg * 8]);
#pragma unroll
          for (int rq = 0; rq < 2; ++rq)
            oacc[c6][rq] = __builtin_amdgcn_mfma_f32_16x16x32_bf16(
                va, pa[rq], oacc[c6][rq], 0, 0, 0);
        }
      }
#endif
    }
  }
  // ---- epilogue: lane (fr,fg): q = q0+rq*16+fr, c = c6*16+fg*4+j ----
#pragma unroll
  for (int rq = 0; rq < 2; ++rq) {
    const float inv = 1.0f / lreg[rq];
    const size_t rowb = (size_t)(tb + q0 + rq * 16 + fr) * 3072 + h * 96;
#pragma unroll
    for (int c6 = 0; c6 < 6; ++c6) {
      u16x4 o;
#pragma unroll
      for (int j = 0; j < 4; ++j) o[j] = f2bf(oacc[c6][rq][j] * inv);
      *(u16x4*)(&O[rowb + c6 * 16 + fg * 4]) = o;
    }
  }
}

// ---------------- launcher ----------------
extern "C" void kernel_launch(void* const* d_in, const int* in_sizes, int n_in,
                              void* d_out, int out_size, void* d_ws,
                              size_t ws_size, hipStream_t stream) {
  const float* X  = (const float*)d_in[0];
  const int*   pos = (const int*)d_in[1];
  const float* Wq = (const float*)d_in[2];
  const float* Wk = (const float*)d_in[3];
  const float* Wv = (const float*)d_in[4];
  const float* Wo = (const float*)d_in[5];
  float* out = (float*)d_out;

  ushort_t* Xb    = (ushort_t*)d_ws;
  ushort_t* Wob   = Xb + 16777216;
  ushort_t* QKV   = Wob + 12582912;
  ushort_t* AO    = QKV + 24117248;
  ushort_t* Wqkvb = (ushort_t*)d_out;   // staged, consumed before O-proj

  k_f32_to_bf16<<<8192, 256, 0, stream>>>(X, Xb, 2097152);
  k_f32_to_bf16<<<8192, 256, 0, stream>>>(Wq, Wqkvb, 2097152);
  k_f32_to_bf16<<<2048, 256, 0, stream>>>(Wk, Wqkvb + 16777216, 524288);
  k_f32_to_bf16<<<1536, 256, 0, stream>>>(Wv, Wqkvb + 20971520, 393216);
  k_f32_to_bf16<<<6144, 256, 0, stream>>>(Wo, Wob, 1572864);

  k_gemm_bt<1><<<dim3(32, 46), 256, 0, stream>>>(Xb, Wqkvb, QKV, 4096, 4096,
                                                 4096, 5888);
  k_rope<<<20480, 256, 0, stream>>>(QKV, pos);
  k_attn<<<dim3(16, 32, 2), 256, 0, stream>>>(QKV, AO);
  k_gemm_bt<0><<<dim3(32, 32), 256, 0, stream>>>(AO, Wob, out, 3072, 3072,
                                                 3072, 4096);
}